// Round 11
// baseline (346.111 us; speedup 1.0000x reference)
//
#include <hip/hip_runtime.h>

// ConvLSTM2D (B=16,T=5,H=W=256,Cin=3,F=8) + BN + LeakyReLU + Dense(8->2)
// TIME-TILED FUSION (round 10 structure) + round-11 fix: h writeback is
// MASKED to zero for out-of-image region pixels. Without it, out-of-image
// pixels convolve real in-image h and become nonzero at t>=1, corrupting the
// SAME-padding zeros the reference expects (r10: absmax 2.8e-2 at borders).
// One kernel: each block computes all 5 timesteps for its 32x16 output tile
// over a 40x24 region (cone grows 1px/step; t=0 exact since h0=0 -> 4px halo).
// h ping-pongs in LDS (42x26 with permanent zero ring), c in registers,
// x restaged per step from global (~134 MB total HBM). 3 MFMA strips at
// x={0,12,24} cover w=40; overlap pixels compute bit-identical duplicates.

#define BB  16
#define TT  5
#define HH  256
#define WW  256
#define CIN 3
#define FF  8
#define GG  32

#define TWO 32     // output tile width
#define THO 16     // output tile height
#define RW  40     // region width  (TWO + 8)
#define RH  24     // region height (THO + 8)
#define LWW 42     // LDS width  (RW + zero ring)
#define LHH 26     // LDS height (RH + zero ring)
#define NR  6      // region rows per wave (RH/4)

#define LOG2E 1.44269504088896340736f

typedef _Float16 half8  __attribute__((ext_vector_type(8)));
typedef _Float16 half4  __attribute__((ext_vector_type(4)));
typedef float    floatx4 __attribute__((ext_vector_type(4)));

__device__ __forceinline__ float frcp(float x) { return __builtin_amdgcn_rcpf(x); }
// z pre-scaled by -log2e:  sigmoid(z0) = 1/(1+2^z)
__device__ __forceinline__ float sig2(float z)  { return frcp(1.0f + __builtin_amdgcn_exp2f(z)); }
// z pre-scaled by +2log2e: tanh(z0) = 1 - 2/(1+2^z)
__device__ __forceinline__ float tanh2(float z) { return 1.0f - 2.0f * frcp(1.0f + __builtin_amdgcn_exp2f(z)); }

#define MFMA(A, B, C) __builtin_amdgcn_mfma_f32_16x16x32_f16((A), (B), (C), 0, 0, 0)

// ---------------------------------------------------------------------------
// 16 B-fragments, activation scale folded per column:
// cols 0..15 (i,f) and 24..31 (o): *(-log2e); cols 16..23 (g): *(+2log2e).
// frag 0..9 = hi (chunks 0..4 x 2 col-halves); frag 10..15 = lo for h-conv
// chunks 2..4 (x-conv lo dropped). MFMA B layout: n = lane&15, k = quad*8+j.
// K-chunks: 0: x taps0-7 (k=tap*4+ci); 1: x tap8 (k=ci);
//           2..4: h taps [4c..4c+3] (k=(tap-4c)*8+ci), taps>8 zero
// ---------------------------------------------------------------------------
__global__ void build_frags(const float* __restrict__ wk,
                            const float* __restrict__ wr,
                            _Float16* __restrict__ blob) {
    const int lane = threadIdx.x & 63;
    const int quad = lane >> 4, nlo = lane & 15;
    for (int chunk = 0; chunk < 5; ++chunk) {
        for (int nh = 0; nh < 2; ++nh) {
            const int n = nh * 16 + nlo;
            const float scale = (n >= 16 && n < 24) ? (2.0f * LOG2E) : (-LOG2E);
            const int frag = chunk * 2 + nh;
            _Float16* dhi = blob + ((size_t)frag * 64 + lane) * 8;
            _Float16* dlo = (chunk >= 2)
                ? blob + ((size_t)(10 + (chunk - 2) * 2 + nh) * 64 + lane) * 8
                : nullptr;
            for (int j = 0; j < 8; ++j) {
                const int k = quad * 8 + j;
                float w = 0.0f;
                if (chunk == 0) {
                    int tap = k >> 2, ci = k & 3;
                    if (ci < 3) w = wk[(tap * 3 + ci) * GG + n];
                } else if (chunk == 1) {
                    if (quad == 0 && j < 3) w = wk[(8 * 3 + j) * GG + n];
                } else {
                    int c = chunk - 2;
                    int tap = c * 4 + quad, ci = j;
                    if (tap < 9) w = wr[(tap * FF + ci) * GG + n];
                }
                w *= scale;
                _Float16 wh = (_Float16)w;
                dhi[j] = wh;
                if (dlo) dlo[j] = (_Float16)(w - (float)wh);
            }
        }
    }
}

// ---------------------------------------------------------------------------
// Fused ConvLSTM: grid (8,16,16)=2048 blocks x 256 thr; block = 32x16 output
// tile, computes all 5 timesteps over its 40x24 region.
// ---------------------------------------------------------------------------
__global__ __launch_bounds__(256) void lstm_fused(
    const float* __restrict__ xg,       // [B,T,H,W,3] fp32
    const _Float16* __restrict__ blob,  // scaled B-fragments
    const float* __restrict__ bias,     // [32] (unscaled)
    const float* __restrict__ gamma, const float* __restrict__ beta,
    const float* __restrict__ mean,  const float* __restrict__ var,
    const float* __restrict__ dw,    const float* __restrict__ db,
    float* __restrict__ out)            // [B,H,W,2]
{
    __shared__ half8 hAs[LHH * LWW];   // h ping
    __shared__ half8 hBs[LHH * LWW];   // h pong
    __shared__ half4 xls[LHH * LWW];   // x tile (3ch + pad), restaged per step

    const int tid  = threadIdx.x;
    const int bx = blockIdx.x, by = blockIdx.y, b = blockIdx.z;
    const int lane = tid & 63, wave = tid >> 6;
    const int quad = lane >> 4, nlo = lane & 15;
    const bool lo8 = (nlo < 8);
    const int fc = nlo & 7;

    // B-fragments -> registers, resident
    half8 bfh[10], bfl[6];
#pragma unroll
    for (int i = 0; i < 10; ++i)
        bfh[i] = *(const half8*)(blob + ((size_t)i * 64 + lane) * 8);
#pragma unroll
    for (int i = 0; i < 6; ++i)
        bfl[i] = *(const half8*)(blob + ((size_t)(10 + i) * 64 + lane) * 8);

    const float bv0 = bias[nlo] * (-LOG2E);
    const float bv1 = bias[16 + nlo] * (lo8 ? 2.0f * LOG2E : -LOG2E);

    // fused-epilogue constants
    const float bn_s = gamma[fc] * rsqrtf(var[fc] + 1e-3f);
    const float bn_b = beta[fc] - mean[fc] * bn_s;
    const float dw0 = dw[fc * 2 + 0], dw1 = dw[fc * 2 + 1];
    const float db0 = db[0], db1 = db[1];

    // zero both h buffers (ring stays zero forever; interior = h0 = 0)
    const half8 hz = {(_Float16)0, (_Float16)0, (_Float16)0, (_Float16)0,
                      (_Float16)0, (_Float16)0, (_Float16)0, (_Float16)0};
    for (int l = tid; l < LHH * LWW; l += 256) { hAs[l] = hz; hBs[l] = hz; }

    // c state in registers: 6 rows x 3 strips x 2 px (overlap px duplicated
    // across strips -> identical updates, benign)
    float c0r[NR][3], c1r[NR][3];
#pragma unroll
    for (int r = 0; r < NR; ++r)
#pragma unroll
        for (int s = 0; s < 3; ++s) { c0r[r][s] = 0.f; c1r[r][s] = 0.f; }

    for (int t = 0; t < TT; ++t) {
        half8* hRd = (t & 1) ? hAs : hBs;   // h(t-1) (zeros at t=0)
        half8* hWr = (t & 1) ? hBs : hAs;   // h(t)

        // ---- stage x region incl. ring (fp32 -> fp16), zero outside image --
        for (int l = tid; l < LHH * LWW; l += 256) {
            int rr = l / LWW, rc = l - rr * LWW;
            int iy = by * THO + rr - 5;
            int ix = bx * TWO + rc - 5;
            half4 vh = {(_Float16)0, (_Float16)0, (_Float16)0, (_Float16)0};
            if ((unsigned)iy < HH && (unsigned)ix < WW) {
                const float* p = xg + (((size_t)(b * TT + t) * HH + iy) * WW + ix) * CIN;
                vh.x = (_Float16)p[0]; vh.y = (_Float16)p[1]; vh.z = (_Float16)p[2];
            }
            xls[l] = vh;
        }
        __syncthreads();

#pragma unroll
        for (int r6 = 0; r6 < NR; ++r6) {
            const int row = wave * NR + r6;     // region row 0..23
#pragma unroll
            for (int s = 0; s < 3; ++s) {
                const int gx0 = s * 12;          // strip origin (region col)
                const int lc  = gx0 + nlo;       // lane's pixel col (A-op m)

                // ---- x A fragments from LDS ----
                const int t0 = 2 * quad, t1 = t0 + 1;
                half4 p = xls[(row + t0 / 3) * LWW + lc + t0 % 3];
                half4 q = xls[(row + t1 / 3) * LWW + lc + t1 % 3];
                half4 sx = xls[(row + 2) * LWW + lc + 2];        // tap 8
                half8 a_xA = (half8){p.x, p.y, p.z, p.w, q.x, q.y, q.z, q.w};
                half8 a_xB = (half8){sx.x, sx.y, sx.z, sx.w, sx.x, sx.y, sx.z, sx.w};

                floatx4 acc0 = {bv0, bv0, bv0, bv0};
                floatx4 acc1 = {bv1, bv1, bv1, bv1};
                acc0 = MFMA(a_xA, bfh[0], acc0);  acc1 = MFMA(a_xA, bfh[1], acc1);
                acc0 = MFMA(a_xB, bfh[2], acc0);  acc1 = MFMA(a_xB, bfh[3], acc1);
                if (t > 0) {
#pragma unroll
                    for (int c = 0; c < 3; ++c) {
                        int tap = c * 4 + quad;
                        if (tap > 8) tap = 8;        // padded taps: B rows zero
                        half8 ah = hRd[(row + tap / 3) * LWW + lc + tap % 3];
                        acc0 = MFMA(ah, bfh[4 + c * 2], acc0);
                        acc1 = MFMA(ah, bfh[5 + c * 2], acc1);
                        acc0 = MFMA(ah, bfl[c * 2 + 0], acc0);
                        acc1 = MFMA(ah, bfl[c * 2 + 1], acc1);
                    }
                }

                // ---- gate phase ----
                // C layout: px m = quad*4+reg, ch = nlo (acc0) / nlo+16 (acc1).
                // ch<8 lanes hold (i,g), ch>=8 hold (f,o): shfl_xor(8) swap.
                float s0 = lo8 ? acc0[2] : acc0[0]; float r0 = __shfl_xor(s0, 8, 64);
                float s1 = lo8 ? acc0[3] : acc0[1]; float r1 = __shfl_xor(s1, 8, 64);
                float s2 = lo8 ? acc1[2] : acc1[0]; float r2 = __shfl_xor(s2, 8, 64);
                float s3 = lo8 ? acc1[3] : acc1[1]; float r3 = __shfl_xor(s3, 8, 64);

                const float zi0 = lo8 ? acc0[0] : r0, zi1 = lo8 ? acc0[1] : r1;
                const float zf0 = lo8 ? r0 : acc0[2], zf1 = lo8 ? r1 : acc0[3];
                const float zg0 = lo8 ? acc1[0] : r2, zg1 = lo8 ? acc1[1] : r3;
                const float zo0 = lo8 ? r2 : acc1[2], zo1 = lo8 ? r3 : acc1[3];

                const float ii0 = sig2(zi0), ff0 = sig2(zf0), gg0 = tanh2(zg0), oo0 = sig2(zo0);
                const float cn0 = ff0 * c0r[r6][s] + ii0 * gg0;
                const float hn0 = oo0 * tanh2(cn0 * (2.0f * LOG2E));
                const float ii1 = sig2(zi1), ff1 = sig2(zf1), gg1 = tanh2(zg1), oo1 = sig2(zo1);
                const float cn1 = ff1 * c1r[r6][s] + ii1 * gg1;
                const float hn1 = oo1 * tanh2(cn1 * (2.0f * LOG2E));
                c0r[r6][s] = cn0; c1r[r6][s] = cn1;

                const int m0 = quad * 4 + (lo8 ? 0 : 2);   // strip-local px
                const int iy  = by * THO + row - 4;         // image row
                const int ix0 = bx * TWO + gx0 + m0 - 4;    // image col (px m0)
                if (t < TT - 1) {
                    // h writeback to LDS interior; OUT-OF-IMAGE PIXELS WRITE 0
                    // (exact SAME padding — the r10 bug was nonzero h here)
                    const bool iny = (unsigned)iy < HH;
                    const int idx = (row + 1) * LWW + (gx0 + m0 + 1);
                    _Float16* hp = (_Float16*)hWr;
                    hp[idx * 8 + fc] =
                        (iny && (unsigned)ix0 < WW) ? (_Float16)hn0 : (_Float16)0;
                    hp[(idx + 1) * 8 + fc] =
                        (iny && (unsigned)(ix0 + 1) < WW) ? (_Float16)hn1 : (_Float16)0;
                } else {
                    // ---- fused epilogue: BN -> LeakyReLU(0.3) -> Dense ----
                    float y0 = bn_s * hn0 + bn_b; y0 = (y0 >= 0.f) ? y0 : 0.3f * y0;
                    float y1 = bn_s * hn1 + bn_b; y1 = (y1 >= 0.f) ? y1 : 0.3f * y1;
                    float p00 = y0 * dw0, p01 = y0 * dw1;
                    float p10 = y1 * dw0, p11 = y1 * dw1;
#pragma unroll
                    for (int m = 1; m <= 4; m <<= 1) {
                        p00 += __shfl_xor(p00, m, 64);
                        p01 += __shfl_xor(p01, m, 64);
                        p10 += __shfl_xor(p10, m, 64);
                        p11 += __shfl_xor(p11, m, 64);
                    }
                    const int j = nlo & 7;
                    if (j < 4) {
                        const int rc = gx0 + m0 + (j >> 1);    // region col
                        const int k  = j & 1;
                        // valid cone: region minus 4-ring = the output tile
                        if (rc >= 4 && rc < 36 && row >= 4 && row < 20) {
                            const int ox = bx * TWO + rc - 4;
                            const int oy = by * THO + row - 4;
                            float val = (j == 0 ? p00 : j == 1 ? p01 : j == 2 ? p10 : p11)
                                        + (k ? db1 : db0);
                            out[((size_t)(b * HH + oy) * WW + ox) * 2 + k] = val;
                        }
                    }
                }
            }
        }
        __syncthreads();   // h writes visible before next step reads; xls reuse safe
    }
}

extern "C" void kernel_launch(void* const* d_in, const int* in_sizes, int n_in,
                              void* d_out, int out_size, void* d_ws, size_t ws_size,
                              hipStream_t stream) {
    const float* x     = (const float*)d_in[0];
    const float* wk    = (const float*)d_in[1];
    const float* wr    = (const float*)d_in[2];
    const float* bias  = (const float*)d_in[3];
    const float* gamma = (const float*)d_in[4];
    const float* beta  = (const float*)d_in[5];
    const float* mean  = (const float*)d_in[6];
    const float* var   = (const float*)d_in[7];
    const float* dw    = (const float*)d_in[8];
    const float* db    = (const float*)d_in[9];
    float* out = (float*)d_out;

    _Float16* blob = (_Float16*)d_ws;   // 16 KB fragment blob

    build_frags<<<1, 64, 0, stream>>>(wk, wr, blob);

    dim3 grid(WW / TWO, HH / THO, BB);   // (8,16,16) = 2048 blocks
    dim3 block(256);
    lstm_fused<<<grid, block, 0, stream>>>(
        x, blob, bias, gamma, beta, mean, var, dw, db, out);
}

// Round 12
// 304.328 us; speedup vs baseline: 1.1373x; 1.1373x over previous
//
#include <hip/hip_runtime.h>

// ConvLSTM2D (B=16,T=5,H=W=256,Cin=3,F=8) + BN + LeakyReLU + Dense(8->2)
// TIME-TILED FUSION v2. r11 (32x16 tile) passed at 285us: VALU-bound on
// 2.25x redundant work + per-group addr math + LDS-latency serialization
// (VGPR=128 too tight to pipeline). r12: 32x32 tile (1.56x redundancy),
// lane-constant tap offsets hoisted, per-row batched LDS loads (21 reads
// in flight before MFMAs), __launch_bounds__(256,2) for a 256-VGPR budget
// (LDS 68.9KB caps at 2 blocks/CU anyway). h ping-pong in LDS w/ zero ring +
// out-of-image zero masking (r11 fix); c in registers; x restaged per step.

#define BB  16
#define TT  5
#define HH  256
#define WW  256
#define CIN 3
#define FF  8
#define GG  32

#define TWO 32     // output tile width
#define THO 32     // output tile height
#define RW  40     // region width  (TWO + 8)
#define RH  40     // region height (THO + 8)
#define LWW 42     // LDS width  (RW + zero ring)
#define LHH 42     // LDS height (RH + zero ring)
#define NR  10     // region rows per wave (RH/4)

#define LOG2E 1.44269504088896340736f

typedef _Float16 half8  __attribute__((ext_vector_type(8)));
typedef _Float16 half4  __attribute__((ext_vector_type(4)));
typedef float    floatx4 __attribute__((ext_vector_type(4)));

__device__ __forceinline__ float frcp(float x) { return __builtin_amdgcn_rcpf(x); }
// z pre-scaled by -log2e:  sigmoid(z0) = 1/(1+2^z)
__device__ __forceinline__ float sig2(float z)  { return frcp(1.0f + __builtin_amdgcn_exp2f(z)); }
// z pre-scaled by +2log2e: tanh(z0) = 1 - 2/(1+2^z)
__device__ __forceinline__ float tanh2(float z) { return 1.0f - 2.0f * frcp(1.0f + __builtin_amdgcn_exp2f(z)); }

#define MFMA(A, B, C) __builtin_amdgcn_mfma_f32_16x16x32_f16((A), (B), (C), 0, 0, 0)

// ---------------------------------------------------------------------------
// 16 B-fragments, activation scale folded per column:
// cols 0..15 (i,f) and 24..31 (o): *(-log2e); cols 16..23 (g): *(+2log2e).
// frag 0..9 = hi (chunks 0..4 x 2 col-halves); frag 10..15 = lo for h-conv
// chunks 2..4 (x-conv lo dropped). MFMA B layout: n = lane&15, k = quad*8+j.
// K-chunks: 0: x taps0-7 (k=tap*4+ci); 1: x tap8 (k=ci);
//           2..4: h taps [4c..4c+3] (k=(tap-4c)*8+ci), taps>8 zero
// ---------------------------------------------------------------------------
__global__ void build_frags(const float* __restrict__ wk,
                            const float* __restrict__ wr,
                            _Float16* __restrict__ blob) {
    const int lane = threadIdx.x & 63;
    const int quad = lane >> 4, nlo = lane & 15;
    for (int chunk = 0; chunk < 5; ++chunk) {
        for (int nh = 0; nh < 2; ++nh) {
            const int n = nh * 16 + nlo;
            const float scale = (n >= 16 && n < 24) ? (2.0f * LOG2E) : (-LOG2E);
            const int frag = chunk * 2 + nh;
            _Float16* dhi = blob + ((size_t)frag * 64 + lane) * 8;
            _Float16* dlo = (chunk >= 2)
                ? blob + ((size_t)(10 + (chunk - 2) * 2 + nh) * 64 + lane) * 8
                : nullptr;
            for (int j = 0; j < 8; ++j) {
                const int k = quad * 8 + j;
                float w = 0.0f;
                if (chunk == 0) {
                    int tap = k >> 2, ci = k & 3;
                    if (ci < 3) w = wk[(tap * 3 + ci) * GG + n];
                } else if (chunk == 1) {
                    if (quad == 0 && j < 3) w = wk[(8 * 3 + j) * GG + n];
                } else {
                    int c = chunk - 2;
                    int tap = c * 4 + quad, ci = j;
                    if (tap < 9) w = wr[(tap * FF + ci) * GG + n];
                }
                w *= scale;
                _Float16 wh = (_Float16)w;
                dhi[j] = wh;
                if (dlo) dlo[j] = (_Float16)(w - (float)wh);
            }
        }
    }
}

// ---------------------------------------------------------------------------
// Fused ConvLSTM: grid (8,8,16)=1024 blocks x 256 thr; block = 32x32 output
// tile, all 5 timesteps over its 40x40 region. Each wave owns 10 region rows.
// ---------------------------------------------------------------------------
__global__ __launch_bounds__(256, 2) void lstm_fused(
    const float* __restrict__ xg,       // [B,T,H,W,3] fp32
    const _Float16* __restrict__ blob,  // scaled B-fragments
    const float* __restrict__ bias,     // [32] (unscaled)
    const float* __restrict__ gamma, const float* __restrict__ beta,
    const float* __restrict__ mean,  const float* __restrict__ var,
    const float* __restrict__ dw,    const float* __restrict__ db,
    float* __restrict__ out)            // [B,H,W,2]
{
    __shared__ half8 hAs[LHH * LWW];   // h ping (28,224 B)
    __shared__ half8 hBs[LHH * LWW];   // h pong
    __shared__ half4 xls[LHH * LWW];   // x tile (3ch + pad), restaged per step

    const int tid  = threadIdx.x;
    const int bx = blockIdx.x, by = blockIdx.y, b = blockIdx.z;
    const int lane = tid & 63, wave = tid >> 6;
    const int quad = lane >> 4, nlo = lane & 15;
    const bool lo8 = (nlo < 8);
    const int fc = nlo & 7;

    // ---- lane-constant LDS tap offsets (hoisted out of all loops) ----
    const int xt0 = 2 * quad, xt1 = xt0 + 1;
    const int xoff0 = (xt0 / 3) * LWW + (xt0 % 3);
    const int xoff1 = (xt1 / 3) * LWW + (xt1 % 3);
    const int xoff2 = 2 * LWW + 2;                    // tap 8
    int hoff[3];
#pragma unroll
    for (int c = 0; c < 3; ++c) {
        int tap = c * 4 + quad;
        if (tap > 8) tap = 8;                         // padded taps: B rows zero
        hoff[c] = (tap / 3) * LWW + (tap % 3);
    }

    // B-fragments -> registers, resident
    half8 bfh[10], bfl[6];
#pragma unroll
    for (int i = 0; i < 10; ++i)
        bfh[i] = *(const half8*)(blob + ((size_t)i * 64 + lane) * 8);
#pragma unroll
    for (int i = 0; i < 6; ++i)
        bfl[i] = *(const half8*)(blob + ((size_t)(10 + i) * 64 + lane) * 8);

    const float bv0 = bias[nlo] * (-LOG2E);
    const float bv1 = bias[16 + nlo] * (lo8 ? 2.0f * LOG2E : -LOG2E);

    // fused-epilogue constants
    const float bn_s = gamma[fc] * rsqrtf(var[fc] + 1e-3f);
    const float bn_b = beta[fc] - mean[fc] * bn_s;
    const float dw0 = dw[fc * 2 + 0], dw1 = dw[fc * 2 + 1];
    const float db0 = db[0], db1 = db[1];

    // zero both h buffers (ring stays zero forever; interior = h0 = 0)
    const half8 hz = {(_Float16)0, (_Float16)0, (_Float16)0, (_Float16)0,
                      (_Float16)0, (_Float16)0, (_Float16)0, (_Float16)0};
    for (int l = tid; l < LHH * LWW; l += 256) { hAs[l] = hz; hBs[l] = hz; }

    // c state in registers: 10 rows x 3 strips x 2 px
    float c0r[NR][3], c1r[NR][3];
#pragma unroll
    for (int r = 0; r < NR; ++r)
#pragma unroll
        for (int s = 0; s < 3; ++s) { c0r[r][s] = 0.f; c1r[r][s] = 0.f; }

    for (int t = 0; t < TT; ++t) {
        half8* hRd = (t & 1) ? hAs : hBs;   // h(t-1) (zeros at t=0)
        half8* hWr = (t & 1) ? hBs : hAs;   // h(t)

        // ---- stage x region incl. ring (fp32 -> fp16), zero outside image --
        for (int l = tid; l < LHH * LWW; l += 256) {
            int rr = l / LWW, rc = l - rr * LWW;
            int iy = by * THO + rr - 5;
            int ix = bx * TWO + rc - 5;
            half4 vh = {(_Float16)0, (_Float16)0, (_Float16)0, (_Float16)0};
            if ((unsigned)iy < HH && (unsigned)ix < WW) {
                const float* p = xg + (((size_t)(b * TT + t) * HH + iy) * WW + ix) * CIN;
                vh.x = (_Float16)p[0]; vh.y = (_Float16)p[1]; vh.z = (_Float16)p[2];
            }
            xls[l] = vh;
        }
        __syncthreads();

#pragma unroll 1
        for (int r10 = 0; r10 < NR; ++r10) {
            const int row = wave * NR + r10;     // region row 0..39
            const int rowbase = row * LWW + nlo;

            // ---- BATCH all LDS loads for the 3 strips of this row ----
            half4 xp[3], xq[3], xs_[3];
            half8 ah[3][3];
#pragma unroll
            for (int s = 0; s < 3; ++s) {
                const int base = rowbase + s * 12;
                xp[s]  = xls[base + xoff0];
                xq[s]  = xls[base + xoff1];
                xs_[s] = xls[base + xoff2];
                if (t > 0) {
#pragma unroll
                    for (int c = 0; c < 3; ++c)
                        ah[s][c] = hRd[base + hoff[c]];
                }
            }

#pragma unroll
            for (int s = 0; s < 3; ++s) {
                const int gx0 = s * 12;          // strip origin (region col)

                half8 a_xA = (half8){xp[s].x, xp[s].y, xp[s].z, xp[s].w,
                                     xq[s].x, xq[s].y, xq[s].z, xq[s].w};
                half8 a_xB = (half8){xs_[s].x, xs_[s].y, xs_[s].z, xs_[s].w,
                                     xs_[s].x, xs_[s].y, xs_[s].z, xs_[s].w};

                floatx4 acc0 = {bv0, bv0, bv0, bv0};
                floatx4 acc1 = {bv1, bv1, bv1, bv1};
                acc0 = MFMA(a_xA, bfh[0], acc0);  acc1 = MFMA(a_xA, bfh[1], acc1);
                acc0 = MFMA(a_xB, bfh[2], acc0);  acc1 = MFMA(a_xB, bfh[3], acc1);
                if (t > 0) {
#pragma unroll
                    for (int c = 0; c < 3; ++c) {
                        acc0 = MFMA(ah[s][c], bfh[4 + c * 2], acc0);
                        acc1 = MFMA(ah[s][c], bfh[5 + c * 2], acc1);
                        acc0 = MFMA(ah[s][c], bfl[c * 2 + 0], acc0);
                        acc1 = MFMA(ah[s][c], bfl[c * 2 + 1], acc1);
                    }
                }

                // ---- gate phase ----
                // C layout: px m = quad*4+reg, ch = nlo (acc0) / nlo+16 (acc1).
                // ch<8 lanes hold (i,g), ch>=8 hold (f,o): shfl_xor(8) swap.
                float s0 = lo8 ? acc0[2] : acc0[0]; float r0 = __shfl_xor(s0, 8, 64);
                float s1 = lo8 ? acc0[3] : acc0[1]; float r1 = __shfl_xor(s1, 8, 64);
                float s2 = lo8 ? acc1[2] : acc1[0]; float r2 = __shfl_xor(s2, 8, 64);
                float s3 = lo8 ? acc1[3] : acc1[1]; float r3 = __shfl_xor(s3, 8, 64);

                const float zi0 = lo8 ? acc0[0] : r0, zi1 = lo8 ? acc0[1] : r1;
                const float zf0 = lo8 ? r0 : acc0[2], zf1 = lo8 ? r1 : acc0[3];
                const float zg0 = lo8 ? acc1[0] : r2, zg1 = lo8 ? acc1[1] : r3;
                const float zo0 = lo8 ? r2 : acc1[2], zo1 = lo8 ? r3 : acc1[3];

                const float ii0 = sig2(zi0), ff0 = sig2(zf0), gg0 = tanh2(zg0), oo0 = sig2(zo0);
                const float cn0 = ff0 * c0r[r10][s] + ii0 * gg0;
                const float hn0 = oo0 * tanh2(cn0 * (2.0f * LOG2E));
                const float ii1 = sig2(zi1), ff1 = sig2(zf1), gg1 = tanh2(zg1), oo1 = sig2(zo1);
                const float cn1 = ff1 * c1r[r10][s] + ii1 * gg1;
                const float hn1 = oo1 * tanh2(cn1 * (2.0f * LOG2E));
                c0r[r10][s] = cn0; c1r[r10][s] = cn1;

                const int m0 = quad * 4 + (lo8 ? 0 : 2);   // strip-local px
                const int iy  = by * THO + row - 4;         // image row
                const int ix0 = bx * TWO + gx0 + m0 - 4;    // image col (px m0)
                if (t < TT - 1) {
                    // h writeback to LDS interior; out-of-image pixels write 0
                    const bool iny = (unsigned)iy < HH;
                    const int idx = (row + 1) * LWW + (gx0 + m0 + 1);
                    _Float16* hp = (_Float16*)hWr;
                    hp[idx * 8 + fc] =
                        (iny && (unsigned)ix0 < WW) ? (_Float16)hn0 : (_Float16)0;
                    hp[(idx + 1) * 8 + fc] =
                        (iny && (unsigned)(ix0 + 1) < WW) ? (_Float16)hn1 : (_Float16)0;
                } else {
                    // ---- fused epilogue: BN -> LeakyReLU(0.3) -> Dense ----
                    float y0 = bn_s * hn0 + bn_b; y0 = (y0 >= 0.f) ? y0 : 0.3f * y0;
                    float y1 = bn_s * hn1 + bn_b; y1 = (y1 >= 0.f) ? y1 : 0.3f * y1;
                    float p00 = y0 * dw0, p01 = y0 * dw1;
                    float p10 = y1 * dw0, p11 = y1 * dw1;
#pragma unroll
                    for (int m = 1; m <= 4; m <<= 1) {
                        p00 += __shfl_xor(p00, m, 64);
                        p01 += __shfl_xor(p01, m, 64);
                        p10 += __shfl_xor(p10, m, 64);
                        p11 += __shfl_xor(p11, m, 64);
                    }
                    const int j = nlo & 7;
                    if (j < 4) {
                        const int rc = gx0 + m0 + (j >> 1);    // region col
                        const int k  = j & 1;
                        // valid cone: region minus 4-ring = the output tile
                        if (rc >= 4 && rc < 36 && row >= 4 && row < 36) {
                            const int ox = bx * TWO + rc - 4;
                            const int oy = by * THO + row - 4;
                            float val = (j == 0 ? p00 : j == 1 ? p01 : j == 2 ? p10 : p11)
                                        + (k ? db1 : db0);
                            out[((size_t)(b * HH + oy) * WW + ox) * 2 + k] = val;
                        }
                    }
                }
            }
        }
        __syncthreads();   // h writes visible before next step reads; xls reuse safe
    }
}

extern "C" void kernel_launch(void* const* d_in, const int* in_sizes, int n_in,
                              void* d_out, int out_size, void* d_ws, size_t ws_size,
                              hipStream_t stream) {
    const float* x     = (const float*)d_in[0];
    const float* wk    = (const float*)d_in[1];
    const float* wr    = (const float*)d_in[2];
    const float* bias  = (const float*)d_in[3];
    const float* gamma = (const float*)d_in[4];
    const float* beta  = (const float*)d_in[5];
    const float* mean  = (const float*)d_in[6];
    const float* var   = (const float*)d_in[7];
    const float* dw    = (const float*)d_in[8];
    const float* db    = (const float*)d_in[9];
    float* out = (float*)d_out;

    _Float16* blob = (_Float16*)d_ws;   // 16 KB fragment blob

    build_frags<<<1, 64, 0, stream>>>(wk, wr, blob);

    dim3 grid(WW / TWO, HH / THO, BB);   // (8,8,16) = 1024 blocks
    dim3 block(256);
    lstm_fused<<<grid, block, 0, stream>>>(
        x, blob, bias, gamma, beta, mean, var, dw, db, out);
}